// Round 6
// baseline (8240.136 us; speedup 1.0000x reference)
//
#include <hip/hip_runtime.h>
#include <math.h>

#define kB 8
#define kN 4096
#define kBN (kB * kN)
#define kK 30
#define kCH 4096  // head row-chunk

// ----------------------------- concat x0 (padded to 8 ch) -----------------
__global__ void concat_x0_kernel(const float* __restrict__ x,
                                 const float* __restrict__ pos,
                                 float* __restrict__ x0p) {
  int e = blockIdx.x * 256 + threadIdx.x;
  if (e >= kBN * 8) return;
  int p = e / 8, c = e % 8;
  float v = 0.f;
  if (c < 3) v = x[(size_t)p * 3 + c];
  else if (c < 6) v = pos[(size_t)p * 3 + (c - 3)];
  x0p[e] = v;
}

// ------------------------------ norms ------------------------------------
template <int C, int CS>
__global__ void norms_kernel(const float* __restrict__ X, float* __restrict__ nrm) {
  int p = blockIdx.x * 256 + threadIdx.x;
  if (p >= kBN) return;
  const float* xp = X + (size_t)p * CS;
  float s = 0.f;
  for (int c = 0; c < C; ++c) s = fmaf(xp[c], xp[c], s);
  nrm[p] = s;
}

// ------------------------------- kNN --------------------------------------
// Q=2 register blocking: each wave owns 2 consecutive queries; one candidate
// ds_read_b128 feeds 8 fmas (2 queries x 4 ch). Block = 256 thr = 4 waves =
// 8 queries. Distances d0/d1[64] in registers; selection per query as before
// (shfl butterfly + group rescan, zero barriers). Distance fma order per
// query is bit-identical to the Q=1 version -> same neighbor sets.
template <int CS>
__global__ __launch_bounds__(256, 2) void knn_kernel(
    const float* __restrict__ X, const float* __restrict__ nrm,
    int* __restrict__ idx_out) {
  __shared__ float chunk[kN * 4];  // 64 KB: [4096 rows][4 ch]

  const int tid = threadIdx.x;
  const int w = tid >> 6;
  const int l = tid & 63;
  const int qglob0 = blockIdx.x * 8 + w * 2;   // wave owns q0, q0+1
  const int b = qglob0 >> 12;
  const int qj0 = qglob0 & (kN - 1);
  const int qj1 = qj0 + 1;
  const float* __restrict__ Xb = X + (size_t)b * kN * CS;
  const float* __restrict__ nrmb = nrm + (size_t)b * kN;

  float d0[64], d1[64];
  #pragma unroll
  for (int m = 0; m < 64; ++m) { d0[m] = 0.f; d1[m] = 0.f; }

  constexpr int NCH = CS / 4;
  for (int c = 0; c < NCH; ++c) {
    if (c) __syncthreads();
    const int c0 = c * 4;
    // stage 4096 rows x 16 B cooperatively (256 thr x 16 rows)
    #pragma unroll
    for (int i = 0; i < 16; ++i) {
      int row = tid + i * 256;
      float4 v = *reinterpret_cast<const float4*>(Xb + (size_t)row * CS + c0);
      *reinterpret_cast<float4*>(&chunk[row * 4]) = v;
    }
    __syncthreads();

    float4 q0 = *reinterpret_cast<const float4*>(&chunk[qj0 * 4]);
    float4 q1 = *reinterpret_cast<const float4*>(&chunk[qj1 * 4]);
    #pragma unroll
    for (int m = 0; m < 64; ++m) {
      float4 f = *reinterpret_cast<const float4*>(&chunk[(m * 64 + l) * 4]);
      d0[m] = fmaf(f.w, q0.w, fmaf(f.z, q0.z, fmaf(f.y, q0.y, fmaf(f.x, q0.x, d0[m]))));
      d1[m] = fmaf(f.w, q1.w, fmaf(f.z, q1.z, fmaf(f.y, q1.y, fmaf(f.x, q1.x, d1[m]))));
    }
  }

  // ---- finalize distances (shared nj read) ----
  const float ni0 = nrmb[qj0];
  const float ni1 = nrmb[qj1];
  #pragma unroll
  for (int m = 0; m < 64; ++m) {
    float nj = nrmb[m * 64 + l];
    d0[m] = fmaf(2.f, d0[m], -ni0) - nj;
    d1[m] = fmaf(2.f, d1[m], -ni1) - nj;
  }

  // ---- per-query selection (30 rounds, zero barriers) ----
#define KNN_SELECT(D, OUTP)                                              \
  {                                                                      \
    float gv[4];                                                         \
    int gm[4];                                                           \
    _Pragma("unroll") for (int g = 0; g < 4; ++g) {                      \
      float bv = -INFINITY;                                              \
      int bm = g * 16;                                                   \
      _Pragma("unroll") for (int mm = 0; mm < 16; ++mm) {                \
        const int m = g * 16 + mm;                                       \
        if (D[m] > bv) { bv = D[m]; bm = m; }                            \
      }                                                                  \
      gv[g] = bv;                                                        \
      gm[g] = bm;                                                        \
    }                                                                    \
    int myout = 0;                                                       \
    for (int k = 0; k < kK; ++k) {                                       \
      float cv = gv[0];                                                  \
      int cm = gm[0];                                                    \
      _Pragma("unroll") for (int g = 1; g < 4; ++g)                      \
        if (gv[g] > cv) { cv = gv[g]; cm = gm[g]; }                      \
      int cj = cm * 64 + l;                                              \
      _Pragma("unroll") for (int off = 32; off > 0; off >>= 1) {         \
        float ov = __shfl_xor(cv, off);                                  \
        int oj = __shfl_xor(cj, off);                                    \
        if (ov > cv || (ov == cv && oj < cj)) { cv = ov; cj = oj; }      \
      }                                                                  \
      if (l == k) myout = cj;                                            \
      if ((cj & 63) == l) {                                              \
        const int om = cj >> 6;                                          \
        const int gsel = om >> 4;                                        \
        _Pragma("unroll") for (int g = 0; g < 4; ++g) {                  \
          if (g == gsel) {                                               \
            float nv = -INFINITY;                                        \
            int nm = g * 16;                                             \
            _Pragma("unroll") for (int mm = 0; mm < 16; ++mm) {          \
              const int m = g * 16 + mm;                                 \
              float dd = (m == om) ? -INFINITY : D[m];                   \
              D[m] = dd;                                                 \
              if (dd > nv) { nv = dd; nm = m; }                          \
            }                                                            \
            gv[g] = nv;                                                  \
            gm[g] = nm;                                                  \
          }                                                              \
        }                                                                \
      }                                                                  \
    }                                                                    \
    if (l < kK) (OUTP)[l] = myout;                                       \
  }

  KNN_SELECT(d0, idx_out + (size_t)qglob0 * kK)
  KNN_SELECT(d1, idx_out + (size_t)(qglob0 + 1) * kK)
#undef KNN_SELECT
}

// -------------------- EdgeConv via U/V decomposition -----------------------
// e = [xi, xj-xi]  =>  e@W1 = xi@(W1a-W1b) + xj@W1b
__global__ void prep_uv_kernel(const float* __restrict__ W1,
                               const float* __restrict__ b1,
                               float* __restrict__ wu, float* __restrict__ b1e,
                               int C, int H1, int CS) {
  const int n2 = 2 * H1;
  int e = blockIdx.x * 256 + threadIdx.x;
  if (e < n2) b1e[e] = (e < H1) ? b1[e] : 0.f;
  if (e >= CS * n2) return;
  int c = e / n2, n = e % n2;
  float v;
  if (c >= C) v = 0.f;
  else if (n < H1) v = W1[(size_t)c * H1 + n] - W1[(size_t)(C + c) * H1 + n];
  else v = W1[(size_t)(C + c) * H1 + (n - H1)];
  wu[e] = v;
}

// gather + GEMM2 + max: block = 2 points x 32 padded edges (rows), 64 cols.
template <int H1>
__global__ __launch_bounds__(256) void gather_gemm2_max_kernel(
    const float* __restrict__ UV, const int* __restrict__ nidx,
    const float* __restrict__ W2, const float* __restrict__ b2,
    float* __restrict__ Y, int H2) {
  __shared__ float As[16][64 + 4];
  __shared__ float Ws[16][64];
  __shared__ float red[16][64];

  const int tid = threadIdx.x;
  const int tx = tid & 15, ty = tid >> 4;
  const int p0 = blockIdx.y * 2;
  const int n0 = blockIdx.x * 64;
  const int N2 = 2 * H1;

  const int r = tid >> 2;
  const int k4g = (tid & 3) * 4;
  const int pt = p0 + (r >> 5);
  int e = r & 31;
  if (e >= kK) e = 0;  // pad rows duplicate edge 0 -> max unchanged
  const int j = nidx[(size_t)pt * kK + e];
  const int jglob = (pt & ~(kN - 1)) + j;  // batch-local -> global row
  const float* __restrict__ Urow = UV + (size_t)pt * N2;
  const float* __restrict__ Vrow = UV + (size_t)jglob * N2 + H1;

  const int wk = tid >> 6;    // 0..3
  const int wn = tid & 63;

  float acc[4][4] = {};

  #pragma unroll
  for (int k0 = 0; k0 < H1; k0 += 16) {
    float4 u4 = *reinterpret_cast<const float4*>(Urow + k0 + k4g);
    float4 v4 = *reinterpret_cast<const float4*>(Vrow + k0 + k4g);
    As[k4g + 0][r] = fmaxf(u4.x + v4.x, 0.f);
    As[k4g + 1][r] = fmaxf(u4.y + v4.y, 0.f);
    As[k4g + 2][r] = fmaxf(u4.z + v4.z, 0.f);
    As[k4g + 3][r] = fmaxf(u4.w + v4.w, 0.f);
    #pragma unroll
    for (int q = 0; q < 4; ++q)
      Ws[wk + q * 4][wn] = W2[(size_t)(k0 + wk + q * 4) * H2 + n0 + wn];
    __syncthreads();
    #pragma unroll
    for (int kk = 0; kk < 16; ++kk) {
      float4 a4 = *reinterpret_cast<const float4*>(&As[kk][ty * 4]);
      float4 b4 = *reinterpret_cast<const float4*>(&Ws[kk][tx * 4]);
      float av[4] = {a4.x, a4.y, a4.z, a4.w};
      float bv[4] = {b4.x, b4.y, b4.z, b4.w};
      #pragma unroll
      for (int i2 = 0; i2 < 4; ++i2)
        #pragma unroll
        for (int j2 = 0; j2 < 4; ++j2)
          acc[i2][j2] = fmaf(av[i2], bv[j2], acc[i2][j2]);
    }
    __syncthreads();
  }

  #pragma unroll
  for (int j2 = 0; j2 < 4; ++j2) {
    float m = fmaxf(fmaxf(acc[0][j2], acc[1][j2]), fmaxf(acc[2][j2], acc[3][j2]));
    red[ty][tx * 4 + j2] = m;
  }
  __syncthreads();
  if (tid < 128) {
    int ptl = tid >> 6, c = tid & 63;
    float m = red[ptl * 8][c];
    #pragma unroll
    for (int q = 1; q < 8; ++q) m = fmaxf(m, red[ptl * 8 + q][c]);
    Y[(size_t)(p0 + ptl) * H2 + n0 + c] = m + b2[n0 + c];
  }
}

// --------------------- fused fe (relu(x4@W1+b1))@W2+b2, col-max ------------
#define FRT 16
__global__ __launch_bounds__(256) void fe_fused_kernel(
    const float* __restrict__ x4, const float* __restrict__ W1,
    const float* __restrict__ b1, const float* __restrict__ W2,
    const float* __restrict__ b2, float* __restrict__ part) {
  __shared__ float xs[FRT][128];
  __shared__ float h1[FRT][1024];
  const int tile = blockIdx.x;
  const int r0 = tile * FRT;
  const int t = threadIdx.x;

  for (int e = t; e < FRT * 32; e += 256) {
    int r = e / 32, c4 = e % 32;
    *reinterpret_cast<float4*>(&xs[r][c4 * 4]) =
        *reinterpret_cast<const float4*>(&x4[(size_t)(r0 + r) * 128 + c4 * 4]);
  }
  __syncthreads();

  float acc[FRT][4];
  {
    float4 bb = *reinterpret_cast<const float4*>(&b1[4 * t]);
    #pragma unroll
    for (int r = 0; r < FRT; ++r) {
      acc[r][0] = bb.x; acc[r][1] = bb.y; acc[r][2] = bb.z; acc[r][3] = bb.w;
    }
  }
  for (int k0 = 0; k0 < 128; k0 += 4) {
    float4 w[4];
    #pragma unroll
    for (int kk = 0; kk < 4; ++kk)
      w[kk] = *reinterpret_cast<const float4*>(&W1[(size_t)(k0 + kk) * 1024 + 4 * t]);
    #pragma unroll
    for (int r = 0; r < FRT; ++r) {
      float4 xv = *reinterpret_cast<const float4*>(&xs[r][k0]);
      float xa[4] = {xv.x, xv.y, xv.z, xv.w};
      #pragma unroll
      for (int kk = 0; kk < 4; ++kk) {
        acc[r][0] = fmaf(xa[kk], w[kk].x, acc[r][0]);
        acc[r][1] = fmaf(xa[kk], w[kk].y, acc[r][1]);
        acc[r][2] = fmaf(xa[kk], w[kk].z, acc[r][2]);
        acc[r][3] = fmaf(xa[kk], w[kk].w, acc[r][3]);
      }
    }
  }
  #pragma unroll
  for (int r = 0; r < FRT; ++r) {
    float4 hv;
    hv.x = fmaxf(acc[r][0], 0.f); hv.y = fmaxf(acc[r][1], 0.f);
    hv.z = fmaxf(acc[r][2], 0.f); hv.w = fmaxf(acc[r][3], 0.f);
    *reinterpret_cast<float4*>(&h1[r][4 * t]) = hv;
  }
  __syncthreads();

  {
    float4 bb = *reinterpret_cast<const float4*>(&b2[4 * t]);
    #pragma unroll
    for (int r = 0; r < FRT; ++r) {
      acc[r][0] = bb.x; acc[r][1] = bb.y; acc[r][2] = bb.z; acc[r][3] = bb.w;
    }
  }
  for (int k0 = 0; k0 < 1024; k0 += 4) {
    float4 w[4];
    #pragma unroll
    for (int kk = 0; kk < 4; ++kk)
      w[kk] = *reinterpret_cast<const float4*>(&W2[(size_t)(k0 + kk) * 1024 + 4 * t]);
    #pragma unroll
    for (int r = 0; r < FRT; ++r) {
      float4 hv = *reinterpret_cast<const float4*>(&h1[r][k0]);
      float ha[4] = {hv.x, hv.y, hv.z, hv.w};
      #pragma unroll
      for (int kk = 0; kk < 4; ++kk) {
        acc[r][0] = fmaf(ha[kk], w[kk].x, acc[r][0]);
        acc[r][1] = fmaf(ha[kk], w[kk].y, acc[r][1]);
        acc[r][2] = fmaf(ha[kk], w[kk].z, acc[r][2]);
        acc[r][3] = fmaf(ha[kk], w[kk].w, acc[r][3]);
      }
    }
  }
  #pragma unroll
  for (int j = 0; j < 4; ++j) {
    float m = -INFINITY;
    #pragma unroll
    for (int r = 0; r < FRT; ++r) m = fmaxf(m, acc[r][j]);
    part[(size_t)tile * 1024 + 4 * t + j] = m;
  }
}

// --------------------------- reduce partials -> g ---------------------------
__global__ void reduce_g_kernel(const float* __restrict__ part, float* __restrict__ g) {
  int e = blockIdx.x * 256 + threadIdx.x;
  if (e >= kB * 1024) return;
  int b = e / 1024, c = e % 1024;
  const int tilesPerBatch = kN / FRT;  // 256
  const float* p = part + (size_t)b * tilesPerBatch * 1024 + c;
  float m = -INFINITY;
  for (int t = 0; t < tilesPerBatch; ++t) m = fmaxf(m, p[(size_t)t * 1024]);
  g[e] = m;
}

// ------------------------------- GEMM --------------------------------------
struct FeatSrc {
  const float* x0; const float* x1; const float* x2;
  const float* x3; const float* x4; const float* g;
};

template <int ASRC>
__device__ __forceinline__ float a_fetch(const float* __restrict__ A,
                                         const FeatSrc& fs, int row, int k, int Kd) {
  if constexpr (ASRC == 0) {
    return A[(size_t)row * Kd + k];
  } else {
    if (k < 6)        return fs.x0[(size_t)row * 8 + k];
    else if (k < 70)  return fs.x1[(size_t)row * 64 + (k - 6)];
    else if (k < 134) return fs.x2[(size_t)row * 64 + (k - 70)];
    else if (k < 198) return fs.x3[(size_t)row * 64 + (k - 134)];
    else if (k < 326) return fs.x4[(size_t)row * 128 + (k - 198)];
    else              return fs.g[(size_t)(row >> 12) * 1024 + (k - 326)];
  }
}

#define GBM 64
#define GBN 64
#define GBK 16

template <int ASRC>
__global__ __launch_bounds__(256) void gemm_kernel(
    const float* __restrict__ A, FeatSrc fs,
    const float* __restrict__ Bm, const float* __restrict__ bias,
    float* __restrict__ out, int row0, int Nn, int Kd, int relu) {
  __shared__ float As[GBK][GBM + 4];
  __shared__ float Bs[GBK][GBN];

  const int tid = threadIdx.x;
  const int tx = tid % 16, ty = tid / 16;
  const int m0 = blockIdx.y * GBM;
  const int n0 = blockIdx.x * GBN;

  float acc[4][4] = {};

  for (int k0 = 0; k0 < Kd; k0 += GBK) {
    #pragma unroll
    for (int r = 0; r < 4; ++r) {
      int ee = tid + r * 256;
      int ar = ee / GBK, ak = ee % GBK;
      int kk = k0 + ak;
      float v = 0.f;
      if (kk < Kd) {
        int arow = (ASRC == 1) ? (row0 + m0 + ar) : (m0 + ar);
        v = a_fetch<ASRC>(A, fs, arow, kk, Kd);
      }
      As[ak][ar] = v;
    }
    #pragma unroll
    for (int r = 0; r < 4; ++r) {
      int ee = tid + r * 256;
      int bk = ee / GBN, bn = ee % GBN;
      int kk = k0 + bk;
      float v = 0.f;
      if (kk < Kd && (n0 + bn) < Nn) v = Bm[(size_t)kk * Nn + n0 + bn];
      Bs[bk][bn] = v;
    }
    __syncthreads();
    #pragma unroll
    for (int kk = 0; kk < GBK; ++kk) {
      float4 a4 = *reinterpret_cast<const float4*>(&As[kk][ty * 4]);
      float4 b4 = *reinterpret_cast<const float4*>(&Bs[kk][tx * 4]);
      float av[4] = {a4.x, a4.y, a4.z, a4.w};
      float bv[4] = {b4.x, b4.y, b4.z, b4.w};
      #pragma unroll
      for (int i2 = 0; i2 < 4; ++i2)
        #pragma unroll
        for (int j2 = 0; j2 < 4; ++j2)
          acc[i2][j2] = fmaf(av[i2], bv[j2], acc[i2][j2]);
    }
    __syncthreads();
  }

  #pragma unroll
  for (int j2 = 0; j2 < 4; ++j2) {
    int n = n0 + tx * 4 + j2;
    if (n >= Nn) continue;
    float bb = bias ? bias[n] : 0.f;
    #pragma unroll
    for (int i2 = 0; i2 < 4; ++i2) {
      float v = acc[i2][j2] + bb;
      if (relu) v = fmaxf(v, 0.f);
      out[(size_t)(m0 + ty * 4 + i2) * Nn + n] = v;
    }
  }
}

// ------------------------------ log_softmax --------------------------------
__global__ void log_softmax_kernel(const float* __restrict__ logits,
                                   float* __restrict__ out, int row0) {
  int r = blockIdx.x * 256 + threadIdx.x;
  if (r >= kCH) return;
  const float* lp = logits + (size_t)r * 13;
  float v[13];
  float m = -INFINITY;
  #pragma unroll
  for (int c = 0; c < 13; ++c) { v[c] = lp[c]; m = fmaxf(m, v[c]); }
  float s = 0.f;
  #pragma unroll
  for (int c = 0; c < 13; ++c) s += expf(v[c] - m);
  float ls = logf(s);
  float* op = out + (size_t)(row0 + r) * 13;
  #pragma unroll
  for (int c = 0; c < 13; ++c) op[c] = v[c] - m - ls;
}

// ------------------------------- launch ------------------------------------
extern "C" void kernel_launch(void* const* d_in, const int* in_sizes, int n_in,
                              void* d_out, int out_size, void* d_ws, size_t ws_size,
                              hipStream_t stream) {
  const float* x    = (const float*)d_in[0];
  const float* pos  = (const float*)d_in[1];
  const float* e1W1 = (const float*)d_in[2];
  const float* e1b1 = (const float*)d_in[3];
  const float* e1W2 = (const float*)d_in[4];
  const float* e1b2 = (const float*)d_in[5];
  const float* e2W1 = (const float*)d_in[6];
  const float* e2b1 = (const float*)d_in[7];
  const float* e2W2 = (const float*)d_in[8];
  const float* e2b2 = (const float*)d_in[9];
  const float* e3W1 = (const float*)d_in[10];
  const float* e3b1 = (const float*)d_in[11];
  const float* e3W2 = (const float*)d_in[12];
  const float* e3b2 = (const float*)d_in[13];
  const float* e4W1 = (const float*)d_in[14];
  const float* e4b1 = (const float*)d_in[15];
  const float* e4W2 = (const float*)d_in[16];
  const float* e4b2 = (const float*)d_in[17];
  const float* feW1 = (const float*)d_in[18];
  const float* feb1 = (const float*)d_in[19];
  const float* feW2 = (const float*)d_in[20];
  const float* feb2 = (const float*)d_in[21];
  const float* h0W  = (const float*)d_in[22];
  const float* h0b  = (const float*)d_in[23];
  const float* h1W  = (const float*)d_in[24];
  const float* h1b  = (const float*)d_in[25];
  const float* h2W  = (const float*)d_in[26];
  const float* h2b  = (const float*)d_in[27];
  const float* h3W  = (const float*)d_in[28];
  const float* h3b  = (const float*)d_in[29];

  float* W = (float*)d_ws;
  size_t off = 0;
  float* x0p  = W + off; off += (size_t)kBN * 8;
  float* x1   = W + off; off += (size_t)kBN * 64;
  float* x2   = W + off; off += (size_t)kBN * 64;
  float* x3   = W + off; off += (size_t)kBN * 64;
  float* x4   = W + off; off += (size_t)kBN * 128;
  float* gmax = W + off; off += (size_t)kB * 1024;
  float* nrm  = W + off; off += (size_t)kBN;
  int*   nidx = (int*)(W + off); off += (size_t)kBN * kK;
  float* wu   = W + off; off += (size_t)64 * 256;
  float* b1e  = W + off; off += 256;
  float* trans = W + off;
  float* uv   = trans;
  float* part = trans;
  float* ping = trans;
  float* pong = ping + (size_t)kCH * 256;
  float* h128 = pong + (size_t)kCH * 256;
  float* lgts = h128 + (size_t)kCH * 128;

  FeatSrc fs{x0p, x1, x2, x3, x4, gmax};

  concat_x0_kernel<<<(kBN * 8 + 255) / 256, 256, 0, stream>>>(x, pos, x0p);

  // ---- edge conv 1: C=6 (CS=8), H1=64, H2=64 ----
  norms_kernel<6, 8><<<(kBN + 255) / 256, 256, 0, stream>>>(x0p, nrm);
  knn_kernel<8><<<kBN / 8, 256, 0, stream>>>(x0p, nrm, nidx);
  prep_uv_kernel<<<(8 * 128 + 255) / 256, 256, 0, stream>>>(e1W1, e1b1, wu, b1e, 6, 64, 8);
  gemm_kernel<0><<<dim3(128 / GBN, kBN / GBM), 256, 0, stream>>>(
      x0p, fs, wu, b1e, uv, 0, 128, 8, 0);
  gather_gemm2_max_kernel<64><<<dim3(1, kBN / 2), 256, 0, stream>>>(
      uv, nidx, e1W2, e1b2, x1, 64);

  // ---- edge conv 2: C=64, H1=64, H2=64 ----
  norms_kernel<64, 64><<<(kBN + 255) / 256, 256, 0, stream>>>(x1, nrm);
  knn_kernel<64><<<kBN / 8, 256, 0, stream>>>(x1, nrm, nidx);
  prep_uv_kernel<<<(64 * 128 + 255) / 256, 256, 0, stream>>>(e2W1, e2b1, wu, b1e, 64, 64, 64);
  gemm_kernel<0><<<dim3(128 / GBN, kBN / GBM), 256, 0, stream>>>(
      x1, fs, wu, b1e, uv, 0, 128, 64, 0);
  gather_gemm2_max_kernel<64><<<dim3(1, kBN / 2), 256, 0, stream>>>(
      uv, nidx, e2W2, e2b2, x2, 64);

  // ---- edge conv 3 ----
  norms_kernel<64, 64><<<(kBN + 255) / 256, 256, 0, stream>>>(x2, nrm);
  knn_kernel<64><<<kBN / 8, 256, 0, stream>>>(x2, nrm, nidx);
  prep_uv_kernel<<<(64 * 128 + 255) / 256, 256, 0, stream>>>(e3W1, e3b1, wu, b1e, 64, 64, 64);
  gemm_kernel<0><<<dim3(128 / GBN, kBN / GBM), 256, 0, stream>>>(
      x2, fs, wu, b1e, uv, 0, 128, 64, 0);
  gather_gemm2_max_kernel<64><<<dim3(1, kBN / 2), 256, 0, stream>>>(
      uv, nidx, e3W2, e3b2, x3, 64);

  // ---- edge conv 4: C=64, H1=128, H2=128 ----
  norms_kernel<64, 64><<<(kBN + 255) / 256, 256, 0, stream>>>(x3, nrm);
  knn_kernel<64><<<kBN / 8, 256, 0, stream>>>(x3, nrm, nidx);
  prep_uv_kernel<<<(64 * 256 + 255) / 256, 256, 0, stream>>>(e4W1, e4b1, wu, b1e, 64, 128, 64);
  gemm_kernel<0><<<dim3(256 / GBN, kBN / GBM), 256, 0, stream>>>(
      x3, fs, wu, b1e, uv, 0, 256, 64, 0);
  gather_gemm2_max_kernel<128><<<dim3(2, kBN / 2), 256, 0, stream>>>(
      uv, nidx, e4W2, e4b2, x4, 128);

  // ---- fe fused + global max ----
  fe_fused_kernel<<<kBN / FRT, 256, 0, stream>>>(x4, feW1, feb1, feW2, feb2, part);
  reduce_g_kernel<<<(kB * 1024 + 255) / 256, 256, 0, stream>>>(part, gmax);

  // ---- head, chunked over rows ----
  for (int c = 0; c < kBN / kCH; ++c) {
    int row0 = c * kCH;
    dim3 gh0(256 / GBN, kCH / GBM);
    gemm_kernel<1><<<gh0, 256, 0, stream>>>(nullptr, fs, h0W, h0b, ping, row0, 256, 1350, 1);
    gemm_kernel<0><<<gh0, 256, 0, stream>>>(ping, fs, h1W, h1b, pong, row0, 256, 256, 1);
    dim3 gh2(128 / GBN, kCH / GBM);
    gemm_kernel<0><<<gh2, 256, 0, stream>>>(pong, fs, h2W, h2b, h128, row0, 128, 256, 1);
    dim3 gh3(1, kCH / GBM);
    gemm_kernel<0><<<gh3, 256, 0, stream>>>(h128, fs, h3W, h3b, lgts, row0, 13, 128, 0);
    log_softmax_kernel<<<(kCH + 255) / 256, 256, 0, stream>>>(lgts, (float*)d_out, row0);
  }
}

// Round 7
// 7662.937 us; speedup vs baseline: 1.0753x; 1.0753x over previous
//
#include <hip/hip_runtime.h>
#include <math.h>

#define kB 8
#define kN 4096
#define kBN (kB * kN)
#define kK 30
#define kCH 4096   // head row-chunk
#define kDQ 2048   // knn D-chunk query rows

// ----------------------------- concat x0 (padded to 8 ch) -----------------
__global__ void concat_x0_kernel(const float* __restrict__ x,
                                 const float* __restrict__ pos,
                                 float* __restrict__ x0p) {
  int e = blockIdx.x * 256 + threadIdx.x;
  if (e >= kBN * 8) return;
  int p = e / 8, c = e % 8;
  float v = 0.f;
  if (c < 3) v = x[(size_t)p * 3 + c];
  else if (c < 6) v = pos[(size_t)p * 3 + (c - 3)];
  x0p[e] = v;
}

// ------------------------------ norms ------------------------------------
template <int C, int CS>
__global__ void norms_kernel(const float* __restrict__ X, float* __restrict__ nrm) {
  int p = blockIdx.x * 256 + threadIdx.x;
  if (p >= kBN) return;
  const float* xp = X + (size_t)p * CS;
  float s = 0.f;
  for (int c = 0; c < C; ++c) s = fmaf(xp[c], xp[c], s);
  nrm[p] = s;
}

// --------------------------- kNN: distance GEMM ----------------------------
// D[i][j] = fmaf(2, dot(x_i,x_j), -ni) - nj for one batch, query rows
// i0..i0+kDQ. Ascending-k scalar fmaf per output -> bit-identical to the
// register-resident quad chain used previously (same neighbor sets).
template <int CS>
__global__ __launch_bounds__(256) void dist_gemm_kernel(
    const float* __restrict__ X, const float* __restrict__ nrm,
    float* __restrict__ D, int i0) {
  __shared__ float As[CS][64 + 4];
  __shared__ float Bs[CS][64 + 4];
  const int tid = threadIdx.x;
  const int tx = tid & 15, ty = tid >> 4;
  const int rI = i0 + blockIdx.y * 64;  // batch-local query row base
  const int cJ = blockIdx.x * 64;       // batch-local candidate col base

  constexpr int QUADS = CS / 4;
  for (int e = tid; e < 64 * QUADS; e += 256) {
    int r = e / QUADS, q = e % QUADS;
    float4 v = *reinterpret_cast<const float4*>(X + (size_t)(rI + r) * CS + q * 4);
    As[q * 4 + 0][r] = v.x; As[q * 4 + 1][r] = v.y;
    As[q * 4 + 2][r] = v.z; As[q * 4 + 3][r] = v.w;
  }
  for (int e = tid; e < 64 * QUADS; e += 256) {
    int r = e / QUADS, q = e % QUADS;
    float4 v = *reinterpret_cast<const float4*>(X + (size_t)(cJ + r) * CS + q * 4);
    Bs[q * 4 + 0][r] = v.x; Bs[q * 4 + 1][r] = v.y;
    Bs[q * 4 + 2][r] = v.z; Bs[q * 4 + 3][r] = v.w;
  }
  __syncthreads();

  float acc[4][4] = {};
  #pragma unroll
  for (int k = 0; k < CS; ++k) {
    float4 a4 = *reinterpret_cast<const float4*>(&As[k][ty * 4]);
    float4 b4 = *reinterpret_cast<const float4*>(&Bs[k][tx * 4]);
    float av[4] = {a4.x, a4.y, a4.z, a4.w};
    float bv[4] = {b4.x, b4.y, b4.z, b4.w};
    #pragma unroll
    for (int i2 = 0; i2 < 4; ++i2)
      #pragma unroll
      for (int j2 = 0; j2 < 4; ++j2)
        acc[i2][j2] = fmaf(av[i2], bv[j2], acc[i2][j2]);
  }

  float ni[4], nj[4];
  #pragma unroll
  for (int i2 = 0; i2 < 4; ++i2) ni[i2] = nrm[rI + ty * 4 + i2];
  #pragma unroll
  for (int j2 = 0; j2 < 4; ++j2) nj[j2] = nrm[cJ + tx * 4 + j2];

  #pragma unroll
  for (int i2 = 0; i2 < 4; ++i2) {
    float4 o;
    o.x = fmaf(2.f, acc[i2][0], -ni[i2]) - nj[0];
    o.y = fmaf(2.f, acc[i2][1], -ni[i2]) - nj[1];
    o.z = fmaf(2.f, acc[i2][2], -ni[i2]) - nj[2];
    o.w = fmaf(2.f, acc[i2][3], -ni[i2]) - nj[3];
    *reinterpret_cast<float4*>(
        &D[(size_t)(blockIdx.y * 64 + ty * 4 + i2) * kN + cJ + tx * 4]) = o;
  }
}

// --------------------------- kNN: selection --------------------------------
// One wave per query; d[64] loaded coalesced from the precomputed D row;
// shfl-butterfly argmax with lowest-index tie-break; zero barriers, no LDS.
__global__ __launch_bounds__(256) void knn_select_kernel(
    const float* __restrict__ D, int* __restrict__ idx_out, int qbase) {
  const int w = threadIdx.x >> 6;
  const int l = threadIdx.x & 63;
  const int q = blockIdx.x * 4 + w;  // chunk-local query
  const float* __restrict__ row = D + (size_t)q * kN;

  float d[64];
  #pragma unroll
  for (int m = 0; m < 64; ++m) d[m] = row[m * 64 + l];

  float gv[4];
  int gm[4];
  #pragma unroll
  for (int g = 0; g < 4; ++g) {
    float bv = -INFINITY;
    int bm = g * 16;
    #pragma unroll
    for (int mm = 0; mm < 16; ++mm) {
      const int m = g * 16 + mm;
      if (d[m] > bv) { bv = d[m]; bm = m; }
    }
    gv[g] = bv;
    gm[g] = bm;
  }

  int myout = 0;
  for (int k = 0; k < kK; ++k) {
    float cv = gv[0];
    int cm = gm[0];
    #pragma unroll
    for (int g = 1; g < 4; ++g)
      if (gv[g] > cv) { cv = gv[g]; cm = gm[g]; }
    int cj = cm * 64 + l;
    #pragma unroll
    for (int off = 32; off > 0; off >>= 1) {
      float ov = __shfl_xor(cv, off);
      int oj = __shfl_xor(cj, off);
      if (ov > cv || (ov == cv && oj < cj)) { cv = ov; cj = oj; }
    }
    if (l == k) myout = cj;
    if ((cj & 63) == l) {
      const int om = cj >> 6;
      const int gsel = om >> 4;
      #pragma unroll
      for (int g = 0; g < 4; ++g) {
        if (g == gsel) {
          float nv = -INFINITY;
          int nm = g * 16;
          #pragma unroll
          for (int mm = 0; mm < 16; ++mm) {
            const int m = g * 16 + mm;
            float dd = (m == om) ? -INFINITY : d[m];
            d[m] = dd;
            if (dd > nv) { nv = dd; nm = m; }
          }
          gv[g] = nv;
          gm[g] = nm;
        }
      }
    }
  }
  if (l < kK) idx_out[(size_t)(qbase + q) * kK + l] = myout;
}

// -------------------- EdgeConv via U/V decomposition -----------------------
// e = [xi, xj-xi]  =>  e@W1 = xi@(W1a-W1b) + xj@W1b
__global__ void prep_uv_kernel(const float* __restrict__ W1,
                               const float* __restrict__ b1,
                               float* __restrict__ wu, float* __restrict__ b1e,
                               int C, int H1, int CS) {
  const int n2 = 2 * H1;
  int e = blockIdx.x * 256 + threadIdx.x;
  if (e < n2) b1e[e] = (e < H1) ? b1[e] : 0.f;
  if (e >= CS * n2) return;
  int c = e / n2, n = e % n2;
  float v;
  if (c >= C) v = 0.f;
  else if (n < H1) v = W1[(size_t)c * H1 + n] - W1[(size_t)(C + c) * H1 + n];
  else v = W1[(size_t)(C + c) * H1 + (n - H1)];
  wu[e] = v;
}

// gather + GEMM2 + max: block = 2 points x 32 padded edges (rows), 64 cols.
template <int H1>
__global__ __launch_bounds__(256) void gather_gemm2_max_kernel(
    const float* __restrict__ UV, const int* __restrict__ nidx,
    const float* __restrict__ W2, const float* __restrict__ b2,
    float* __restrict__ Y, int H2) {
  __shared__ float As[16][64 + 4];
  __shared__ float Ws[16][64];
  __shared__ float red[16][64];

  const int tid = threadIdx.x;
  const int tx = tid & 15, ty = tid >> 4;
  const int p0 = blockIdx.y * 2;
  const int n0 = blockIdx.x * 64;
  const int N2 = 2 * H1;

  const int r = tid >> 2;
  const int k4g = (tid & 3) * 4;
  const int pt = p0 + (r >> 5);
  int e = r & 31;
  if (e >= kK) e = 0;  // pad rows duplicate edge 0 -> max unchanged
  const int j = nidx[(size_t)pt * kK + e];
  const int jglob = (pt & ~(kN - 1)) + j;  // batch-local -> global row
  const float* __restrict__ Urow = UV + (size_t)pt * N2;
  const float* __restrict__ Vrow = UV + (size_t)jglob * N2 + H1;

  const int wk = tid >> 6;
  const int wn = tid & 63;

  float acc[4][4] = {};

  #pragma unroll
  for (int k0 = 0; k0 < H1; k0 += 16) {
    float4 u4 = *reinterpret_cast<const float4*>(Urow + k0 + k4g);
    float4 v4 = *reinterpret_cast<const float4*>(Vrow + k0 + k4g);
    As[k4g + 0][r] = fmaxf(u4.x + v4.x, 0.f);
    As[k4g + 1][r] = fmaxf(u4.y + v4.y, 0.f);
    As[k4g + 2][r] = fmaxf(u4.z + v4.z, 0.f);
    As[k4g + 3][r] = fmaxf(u4.w + v4.w, 0.f);
    #pragma unroll
    for (int q = 0; q < 4; ++q)
      Ws[wk + q * 4][wn] = W2[(size_t)(k0 + wk + q * 4) * H2 + n0 + wn];
    __syncthreads();
    #pragma unroll
    for (int kk = 0; kk < 16; ++kk) {
      float4 a4 = *reinterpret_cast<const float4*>(&As[kk][ty * 4]);
      float4 b4 = *reinterpret_cast<const float4*>(&Ws[kk][tx * 4]);
      float av[4] = {a4.x, a4.y, a4.z, a4.w};
      float bv[4] = {b4.x, b4.y, b4.z, b4.w};
      #pragma unroll
      for (int i2 = 0; i2 < 4; ++i2)
        #pragma unroll
        for (int j2 = 0; j2 < 4; ++j2)
          acc[i2][j2] = fmaf(av[i2], bv[j2], acc[i2][j2]);
    }
    __syncthreads();
  }

  #pragma unroll
  for (int j2 = 0; j2 < 4; ++j2) {
    float m = fmaxf(fmaxf(acc[0][j2], acc[1][j2]), fmaxf(acc[2][j2], acc[3][j2]));
    red[ty][tx * 4 + j2] = m;
  }
  __syncthreads();
  if (tid < 128) {
    int ptl = tid >> 6, c = tid & 63;
    float m = red[ptl * 8][c];
    #pragma unroll
    for (int q = 1; q < 8; ++q) m = fmaxf(m, red[ptl * 8 + q][c]);
    Y[(size_t)(p0 + ptl) * H2 + n0 + c] = m + b2[n0 + c];
  }
}

// --------------------- fused fe (relu(x4@W1+b1))@W2+b2, col-max ------------
#define FRT 16
__global__ __launch_bounds__(256) void fe_fused_kernel(
    const float* __restrict__ x4, const float* __restrict__ W1,
    const float* __restrict__ b1, const float* __restrict__ W2,
    const float* __restrict__ b2, float* __restrict__ part) {
  __shared__ float xs[FRT][128];
  __shared__ float h1[FRT][1024];
  const int tile = blockIdx.x;
  const int r0 = tile * FRT;
  const int t = threadIdx.x;

  for (int e = t; e < FRT * 32; e += 256) {
    int r = e / 32, c4 = e % 32;
    *reinterpret_cast<float4*>(&xs[r][c4 * 4]) =
        *reinterpret_cast<const float4*>(&x4[(size_t)(r0 + r) * 128 + c4 * 4]);
  }
  __syncthreads();

  float acc[FRT][4];
  {
    float4 bb = *reinterpret_cast<const float4*>(&b1[4 * t]);
    #pragma unroll
    for (int r = 0; r < FRT; ++r) {
      acc[r][0] = bb.x; acc[r][1] = bb.y; acc[r][2] = bb.z; acc[r][3] = bb.w;
    }
  }
  for (int k0 = 0; k0 < 128; k0 += 4) {
    float4 w[4];
    #pragma unroll
    for (int kk = 0; kk < 4; ++kk)
      w[kk] = *reinterpret_cast<const float4*>(&W1[(size_t)(k0 + kk) * 1024 + 4 * t]);
    #pragma unroll
    for (int r = 0; r < FRT; ++r) {
      float4 xv = *reinterpret_cast<const float4*>(&xs[r][k0]);
      float xa[4] = {xv.x, xv.y, xv.z, xv.w};
      #pragma unroll
      for (int kk = 0; kk < 4; ++kk) {
        acc[r][0] = fmaf(xa[kk], w[kk].x, acc[r][0]);
        acc[r][1] = fmaf(xa[kk], w[kk].y, acc[r][1]);
        acc[r][2] = fmaf(xa[kk], w[kk].z, acc[r][2]);
        acc[r][3] = fmaf(xa[kk], w[kk].w, acc[r][3]);
      }
    }
  }
  #pragma unroll
  for (int r = 0; r < FRT; ++r) {
    float4 hv;
    hv.x = fmaxf(acc[r][0], 0.f); hv.y = fmaxf(acc[r][1], 0.f);
    hv.z = fmaxf(acc[r][2], 0.f); hv.w = fmaxf(acc[r][3], 0.f);
    *reinterpret_cast<float4*>(&h1[r][4 * t]) = hv;
  }
  __syncthreads();

  {
    float4 bb = *reinterpret_cast<const float4*>(&b2[4 * t]);
    #pragma unroll
    for (int r = 0; r < FRT; ++r) {
      acc[r][0] = bb.x; acc[r][1] = bb.y; acc[r][2] = bb.z; acc[r][3] = bb.w;
    }
  }
  for (int k0 = 0; k0 < 1024; k0 += 4) {
    float4 w[4];
    #pragma unroll
    for (int kk = 0; kk < 4; ++kk)
      w[kk] = *reinterpret_cast<const float4*>(&W2[(size_t)(k0 + kk) * 1024 + 4 * t]);
    #pragma unroll
    for (int r = 0; r < FRT; ++r) {
      float4 hv = *reinterpret_cast<const float4*>(&h1[r][k0]);
      float ha[4] = {hv.x, hv.y, hv.z, hv.w};
      #pragma unroll
      for (int kk = 0; kk < 4; ++kk) {
        acc[r][0] = fmaf(ha[kk], w[kk].x, acc[r][0]);
        acc[r][1] = fmaf(ha[kk], w[kk].y, acc[r][1]);
        acc[r][2] = fmaf(ha[kk], w[kk].z, acc[r][2]);
        acc[r][3] = fmaf(ha[kk], w[kk].w, acc[r][3]);
      }
    }
  }
  #pragma unroll
  for (int j = 0; j < 4; ++j) {
    float m = -INFINITY;
    #pragma unroll
    for (int r = 0; r < FRT; ++r) m = fmaxf(m, acc[r][j]);
    part[(size_t)tile * 1024 + 4 * t + j] = m;
  }
}

// --------------------------- reduce partials -> g ---------------------------
__global__ void reduce_g_kernel(const float* __restrict__ part, float* __restrict__ g) {
  int e = blockIdx.x * 256 + threadIdx.x;
  if (e >= kB * 1024) return;
  int b = e / 1024, c = e % 1024;
  const int tilesPerBatch = kN / FRT;  // 256
  const float* p = part + (size_t)b * tilesPerBatch * 1024 + c;
  float m = -INFINITY;
  for (int t = 0; t < tilesPerBatch; ++t) m = fmaxf(m, p[(size_t)t * 1024]);
  g[e] = m;
}

// ------------------------------- GEMM --------------------------------------
struct FeatSrc {
  const float* x0; const float* x1; const float* x2;
  const float* x3; const float* x4; const float* g;
};

template <int ASRC>
__device__ __forceinline__ float a_fetch(const float* __restrict__ A,
                                         const FeatSrc& fs, int row, int k, int Kd) {
  if constexpr (ASRC == 0) {
    return A[(size_t)row * Kd + k];
  } else {
    if (k < 6)        return fs.x0[(size_t)row * 8 + k];
    else if (k < 70)  return fs.x1[(size_t)row * 64 + (k - 6)];
    else if (k < 134) return fs.x2[(size_t)row * 64 + (k - 70)];
    else if (k < 198) return fs.x3[(size_t)row * 64 + (k - 134)];
    else if (k < 326) return fs.x4[(size_t)row * 128 + (k - 198)];
    else              return fs.g[(size_t)(row >> 12) * 1024 + (k - 326)];
  }
}

#define GBM 64
#define GBN 64
#define GBK 16

template <int ASRC>
__global__ __launch_bounds__(256) void gemm_kernel(
    const float* __restrict__ A, FeatSrc fs,
    const float* __restrict__ Bm, const float* __restrict__ bias,
    float* __restrict__ out, int row0, int Nn, int Kd, int relu) {
  __shared__ float As[GBK][GBM + 4];
  __shared__ float Bs[GBK][GBN];

  const int tid = threadIdx.x;
  const int tx = tid % 16, ty = tid / 16;
  const int m0 = blockIdx.y * GBM;
  const int n0 = blockIdx.x * GBN;

  float acc[4][4] = {};

  for (int k0 = 0; k0 < Kd; k0 += GBK) {
    #pragma unroll
    for (int r = 0; r < 4; ++r) {
      int ee = tid + r * 256;
      int ar = ee / GBK, ak = ee % GBK;
      int kk = k0 + ak;
      float v = 0.f;
      if (kk < Kd) {
        int arow = (ASRC == 1) ? (row0 + m0 + ar) : (m0 + ar);
        v = a_fetch<ASRC>(A, fs, arow, kk, Kd);
      }
      As[ak][ar] = v;
    }
    #pragma unroll
    for (int r = 0; r < 4; ++r) {
      int ee = tid + r * 256;
      int bk = ee / GBN, bn = ee % GBN;
      int kk = k0 + bk;
      float v = 0.f;
      if (kk < Kd && (n0 + bn) < Nn) v = Bm[(size_t)kk * Nn + n0 + bn];
      Bs[bk][bn] = v;
    }
    __syncthreads();
    #pragma unroll
    for (int kk = 0; kk < GBK; ++kk) {
      float4 a4 = *reinterpret_cast<const float4*>(&As[kk][ty * 4]);
      float4 b4 = *reinterpret_cast<const float4*>(&Bs[kk][tx * 4]);
      float av[4] = {a4.x, a4.y, a4.z, a4.w};
      float bv[4] = {b4.x, b4.y, b4.z, b4.w};
      #pragma unroll
      for (int i2 = 0; i2 < 4; ++i2)
        #pragma unroll
        for (int j2 = 0; j2 < 4; ++j2)
          acc[i2][j2] = fmaf(av[i2], bv[j2], acc[i2][j2]);
    }
    __syncthreads();
  }

  #pragma unroll
  for (int j2 = 0; j2 < 4; ++j2) {
    int n = n0 + tx * 4 + j2;
    if (n >= Nn) continue;
    float bb = bias ? bias[n] : 0.f;
    #pragma unroll
    for (int i2 = 0; i2 < 4; ++i2) {
      float v = acc[i2][j2] + bb;
      if (relu) v = fmaxf(v, 0.f);
      out[(size_t)(m0 + ty * 4 + i2) * Nn + n] = v;
    }
  }
}

// ------------------------------ log_softmax --------------------------------
__global__ void log_softmax_kernel(const float* __restrict__ logits,
                                   float* __restrict__ out, int row0) {
  int r = blockIdx.x * 256 + threadIdx.x;
  if (r >= kCH) return;
  const float* lp = logits + (size_t)r * 13;
  float v[13];
  float m = -INFINITY;
  #pragma unroll
  for (int c = 0; c < 13; ++c) { v[c] = lp[c]; m = fmaxf(m, v[c]); }
  float s = 0.f;
  #pragma unroll
  for (int c = 0; c < 13; ++c) s += expf(v[c] - m);
  float ls = logf(s);
  float* op = out + (size_t)(row0 + r) * 13;
  #pragma unroll
  for (int c = 0; c < 13; ++c) op[c] = v[c] - m - ls;
}

// ------------------------------- launch ------------------------------------
static void run_knn(const float* X, const float* nrm, float* Dbuf, int* nidx,
                    int CS, hipStream_t stream) {
  for (int b = 0; b < kB; ++b) {
    for (int h = 0; h < kN / kDQ; ++h) {
      if (CS == 8)
        dist_gemm_kernel<8><<<dim3(kN / 64, kDQ / 64), 256, 0, stream>>>(
            X + (size_t)b * kN * 8, nrm + (size_t)b * kN, Dbuf, h * kDQ);
      else
        dist_gemm_kernel<64><<<dim3(kN / 64, kDQ / 64), 256, 0, stream>>>(
            X + (size_t)b * kN * 64, nrm + (size_t)b * kN, Dbuf, h * kDQ);
      knn_select_kernel<<<kDQ / 4, 256, 0, stream>>>(Dbuf, nidx,
                                                     b * kN + h * kDQ);
    }
  }
}

extern "C" void kernel_launch(void* const* d_in, const int* in_sizes, int n_in,
                              void* d_out, int out_size, void* d_ws, size_t ws_size,
                              hipStream_t stream) {
  const float* x    = (const float*)d_in[0];
  const float* pos  = (const float*)d_in[1];
  const float* e1W1 = (const float*)d_in[2];
  const float* e1b1 = (const float*)d_in[3];
  const float* e1W2 = (const float*)d_in[4];
  const float* e1b2 = (const float*)d_in[5];
  const float* e2W1 = (const float*)d_in[6];
  const float* e2b1 = (const float*)d_in[7];
  const float* e2W2 = (const float*)d_in[8];
  const float* e2b2 = (const float*)d_in[9];
  const float* e3W1 = (const float*)d_in[10];
  const float* e3b1 = (const float*)d_in[11];
  const float* e3W2 = (const float*)d_in[12];
  const float* e3b2 = (const float*)d_in[13];
  const float* e4W1 = (const float*)d_in[14];
  const float* e4b1 = (const float*)d_in[15];
  const float* e4W2 = (const float*)d_in[16];
  const float* e4b2 = (const float*)d_in[17];
  const float* feW1 = (const float*)d_in[18];
  const float* feb1 = (const float*)d_in[19];
  const float* feW2 = (const float*)d_in[20];
  const float* feb2 = (const float*)d_in[21];
  const float* h0W  = (const float*)d_in[22];
  const float* h0b  = (const float*)d_in[23];
  const float* h1W  = (const float*)d_in[24];
  const float* h1b  = (const float*)d_in[25];
  const float* h2W  = (const float*)d_in[26];
  const float* h2b  = (const float*)d_in[27];
  const float* h3W  = (const float*)d_in[28];
  const float* h3b  = (const float*)d_in[29];

  float* W = (float*)d_ws;
  size_t off = 0;
  float* x0p  = W + off; off += (size_t)kBN * 8;
  float* x1   = W + off; off += (size_t)kBN * 64;
  float* x2   = W + off; off += (size_t)kBN * 64;
  float* x3   = W + off; off += (size_t)kBN * 64;
  float* x4   = W + off; off += (size_t)kBN * 128;
  float* gmax = W + off; off += (size_t)kB * 1024;
  float* nrm  = W + off; off += (size_t)kBN;
  int*   nidx = (int*)(W + off); off += (size_t)kBN * kK;
  float* wu   = W + off; off += (size_t)64 * 256;
  float* b1e  = W + off; off += 256;
  // transient union: D chunk (32MB) / uv (<=33.5MB) / fe partials / head bufs
  float* trans = W + off;
  float* Dbuf = trans;                       // kDQ * kN = 32 MB
  float* uv   = trans;
  float* part = trans;
  float* ping = trans;
  float* pong = ping + (size_t)kCH * 256;
  float* h128 = pong + (size_t)kCH * 256;
  float* lgts = h128 + (size_t)kCH * 128;

  FeatSrc fs{x0p, x1, x2, x3, x4, gmax};

  concat_x0_kernel<<<(kBN * 8 + 255) / 256, 256, 0, stream>>>(x, pos, x0p);

  // ---- edge conv 1: C=6 (CS=8), H1=64, H2=64 ----
  norms_kernel<6, 8><<<(kBN + 255) / 256, 256, 0, stream>>>(x0p, nrm);
  run_knn(x0p, nrm, Dbuf, nidx, 8, stream);
  prep_uv_kernel<<<(8 * 128 + 255) / 256, 256, 0, stream>>>(e1W1, e1b1, wu, b1e, 6, 64, 8);
  gemm_kernel<0><<<dim3(128 / GBN, kBN / GBM), 256, 0, stream>>>(
      x0p, fs, wu, b1e, uv, 0, 128, 8, 0);
  gather_gemm2_max_kernel<64><<<dim3(1, kBN / 2), 256, 0, stream>>>(
      uv, nidx, e1W2, e1b2, x1, 64);

  // ---- edge conv 2: C=64, H1=64, H2=64 ----
  norms_kernel<64, 64><<<(kBN + 255) / 256, 256, 0, stream>>>(x1, nrm);
  run_knn(x1, nrm, Dbuf, nidx, 64, stream);
  prep_uv_kernel<<<(64 * 128 + 255) / 256, 256, 0, stream>>>(e2W1, e2b1, wu, b1e, 64, 64, 64);
  gemm_kernel<0><<<dim3(128 / GBN, kBN / GBM), 256, 0, stream>>>(
      x1, fs, wu, b1e, uv, 0, 128, 64, 0);
  gather_gemm2_max_kernel<64><<<dim3(1, kBN / 2), 256, 0, stream>>>(
      uv, nidx, e2W2, e2b2, x2, 64);

  // ---- edge conv 3 ----
  norms_kernel<64, 64><<<(kBN + 255) / 256, 256, 0, stream>>>(x2, nrm);
  run_knn(x2, nrm, Dbuf, nidx, 64, stream);
  prep_uv_kernel<<<(64 * 128 + 255) / 256, 256, 0, stream>>>(e3W1, e3b1, wu, b1e, 64, 64, 64);
  gemm_kernel<0><<<dim3(128 / GBN, kBN / GBM), 256, 0, stream>>>(
      x2, fs, wu, b1e, uv, 0, 128, 64, 0);
  gather_gemm2_max_kernel<64><<<dim3(1, kBN / 2), 256, 0, stream>>>(
      uv, nidx, e3W2, e3b2, x3, 64);

  // ---- edge conv 4: C=64, H1=128, H2=128 ----
  norms_kernel<64, 64><<<(kBN + 255) / 256, 256, 0, stream>>>(x3, nrm);
  run_knn(x3, nrm, Dbuf, nidx, 64, stream);
  prep_uv_kernel<<<(64 * 256 + 255) / 256, 256, 0, stream>>>(e4W1, e4b1, wu, b1e, 64, 128, 64);
  gemm_kernel<0><<<dim3(256 / GBN, kBN / GBM), 256, 0, stream>>>(
      x3, fs, wu, b1e, uv, 0, 256, 64, 0);
  gather_gemm2_max_kernel<128><<<dim3(2, kBN / 2), 256, 0, stream>>>(
      uv, nidx, e4W2, e4b2, x4, 128);

  // ---- fe fused + global max ----
  fe_fused_kernel<<<kBN / FRT, 256, 0, stream>>>(x4, feW1, feb1, feW2, feb2, part);
  reduce_g_kernel<<<(kB * 1024 + 255) / 256, 256, 0, stream>>>(part, gmax);

  // ---- head, chunked over rows ----
  for (int c = 0; c < kBN / kCH; ++c) {
    int row0 = c * kCH;
    dim3 gh0(256 / GBN, kCH / GBM);
    gemm_kernel<1><<<gh0, 256, 0, stream>>>(nullptr, fs, h0W, h0b, ping, row0, 256, 1350, 1);
    gemm_kernel<0><<<gh0, 256, 0, stream>>>(ping, fs, h1W, h1b, pong, row0, 256, 256, 1);
    dim3 gh2(128 / GBN, kCH / GBM);
    gemm_kernel<0><<<gh2, 256, 0, stream>>>(pong, fs, h2W, h2b, h128, row0, 128, 256, 1);
    dim3 gh3(1, kCH / GBM);
    gemm_kernel<0><<<gh3, 256, 0, stream>>>(h128, fs, h3W, h3b, lgts, row0, 13, 128, 0);
    log_softmax_kernel<<<(kCH + 255) / 256, 256, 0, stream>>>(lgts, (float*)d_out, row0);
  }
}